// Round 1
// baseline (453.644 us; speedup 1.0000x reference)
//
#include <hip/hip_runtime.h>
#include <math.h>

#define N1 4096
#define N2 1024
#define C1 128
#define C2 256
#define CIN 384
#define H 256
#define BATCH 16
#define BN_EPS 1e-5f

// ---------------- KNN: 3 nearest neighbors + inverse-distance weights ----------------
__global__ __launch_bounds__(256)
void knn_kernel(const float* __restrict__ c1, const float* __restrict__ c2,
                int* __restrict__ idx_out, float* __restrict__ w_out) {
    __shared__ float sx[N2], sy[N2], sz[N2], sq[N2];
    const int b = blockIdx.y;
    const float* c2b = c2 + (size_t)b * 3 * N2;
    for (int j = threadIdx.x; j < N2; j += blockDim.x) {
        float x = c2b[j], y = c2b[N2 + j], z = c2b[2 * N2 + j];
        sx[j] = x; sy[j] = y; sz[j] = z;
        sq[j] = x * x + y * y + z * z;
    }
    __syncthreads();

    const int n = blockIdx.x * blockDim.x + threadIdx.x;
    const float* c1b = c1 + (size_t)b * 3 * N1;
    const float x = c1b[n], y = c1b[N1 + n], z = c1b[2 * N1 + n];
    const float s1 = x * x + y * y + z * z;

    float d0 = 3.4e38f, d1 = 3.4e38f, d2 = 3.4e38f;
    int i0 = 0, i1 = 0, i2 = 0;
    #pragma unroll 4
    for (int j = 0; j < N2; ++j) {
        float dot = x * sx[j] + y * sy[j] + z * sz[j];
        float d = s1 + sq[j] - 2.0f * dot;
        if (d < d2) {
            if (d < d1) {
                d2 = d1; i2 = i1;
                if (d < d0) { d1 = d0; i1 = i0; d0 = d; i0 = j; }
                else        { d1 = d;  i1 = j; }
            } else { d2 = d; i2 = j; }
        }
    }
    float r0 = 1.0f / (d0 + 1e-8f);
    float r1 = 1.0f / (d1 + 1e-8f);
    float r2 = 1.0f / (d2 + 1e-8f);
    float rs = r0 + r1 + r2;
    size_t base = ((size_t)b * N1 + n) * 3;
    idx_out[base + 0] = i0; idx_out[base + 1] = i1; idx_out[base + 2] = i2;
    w_out[base + 0] = r0 / rs; w_out[base + 1] = r1 / rs; w_out[base + 2] = r2 / rs;
}

// ---------------- Interpolation: F[b][c][n] = sum_k w_k * f2[b][c][idx_k] ----------------
__global__ __launch_bounds__(256)
void interp_kernel(const float* __restrict__ f2, const int* __restrict__ idx,
                   const float* __restrict__ w, float* __restrict__ F) {
    const int b = blockIdx.z;
    const int c0 = blockIdx.y * 64;
    const int n = blockIdx.x * blockDim.x + threadIdx.x;
    size_t base = ((size_t)b * N1 + n) * 3;
    const int i0 = idx[base], i1 = idx[base + 1], i2 = idx[base + 2];
    const float w0 = w[base], w1 = w[base + 1], w2 = w[base + 2];
    const float* f2b = f2 + (size_t)b * C2 * N2;
    float* Fb = F + (size_t)b * C2 * N1;
    #pragma unroll 4
    for (int c = c0; c < c0 + 64; ++c) {
        const float* row = f2b + (size_t)c * N2;
        Fb[(size_t)c * N1 + n] = w0 * row[i0] + w1 * row[i1] + w2 * row[i2];
    }
}

// ---------------- Tiled f32 GEMM: Y[b][m][n] = sum_c W[m][c]*X[b][c][n] + bias[m] ----------------
// X rows c<ksplit come from X0, else X1 (row c-ksplit). DO_BN applies relu(x*scale[c]+shift[c]) on load.
template<int K, bool DO_BN>
__global__ __launch_bounds__(256)
void gemm_kernel(const float* __restrict__ W, const float* __restrict__ bias,
                 const float* __restrict__ X0, const float* __restrict__ X1,
                 int ksplit, long x0_bstride, long x1_bstride,
                 const float* __restrict__ scale, const float* __restrict__ shift,
                 float* __restrict__ Y) {
    __shared__ float As[16][128];   // [k][m]
    __shared__ float Bs[16][128];   // [k][n]

    const int tid = threadIdx.x;
    const int tx = tid & 15, ty = tid >> 4;
    const int n0 = blockIdx.x * 128;
    const int m0 = blockIdx.y * 128;
    const int b  = blockIdx.z;

    const float* X0b = X0 + (size_t)b * x0_bstride;
    const float* X1b = X1 ? (X1 + (size_t)b * x1_bstride) : X0;

    const int am  = tid >> 1;
    const int akq = (tid & 1) * 8;
    const int bk  = tid >> 4;
    const int bnq = (tid & 15) * 8;

    float acc[8][8];
    #pragma unroll
    for (int i = 0; i < 8; ++i)
        #pragma unroll
        for (int j = 0; j < 8; ++j) acc[i][j] = 0.f;

    for (int k0 = 0; k0 < K; k0 += 16) {
        const float* wp = W + (size_t)(m0 + am) * K + k0 + akq;
        float4 a0 = *(const float4*)wp;
        float4 a1 = *(const float4*)(wp + 4);

        const int c = k0 + bk;
        const float* src = (c < ksplit) ? (X0b + (size_t)c * N1)
                                        : (X1b + (size_t)(c - ksplit) * N1);
        float4 b0 = *(const float4*)(src + n0 + bnq);
        float4 b1 = *(const float4*)(src + n0 + bnq + 4);
        if (DO_BN) {
            const float sc = scale[c], sh = shift[c];
            b0.x = fmaxf(fmaf(b0.x, sc, sh), 0.f);
            b0.y = fmaxf(fmaf(b0.y, sc, sh), 0.f);
            b0.z = fmaxf(fmaf(b0.z, sc, sh), 0.f);
            b0.w = fmaxf(fmaf(b0.w, sc, sh), 0.f);
            b1.x = fmaxf(fmaf(b1.x, sc, sh), 0.f);
            b1.y = fmaxf(fmaf(b1.y, sc, sh), 0.f);
            b1.z = fmaxf(fmaf(b1.z, sc, sh), 0.f);
            b1.w = fmaxf(fmaf(b1.w, sc, sh), 0.f);
        }

        __syncthreads();
        As[akq + 0][am] = a0.x; As[akq + 1][am] = a0.y;
        As[akq + 2][am] = a0.z; As[akq + 3][am] = a0.w;
        As[akq + 4][am] = a1.x; As[akq + 5][am] = a1.y;
        As[akq + 6][am] = a1.z; As[akq + 7][am] = a1.w;
        *(float4*)&Bs[bk][bnq]     = b0;
        *(float4*)&Bs[bk][bnq + 4] = b1;
        __syncthreads();

        #pragma unroll
        for (int kk = 0; kk < 16; ++kk) {
            float4 av0 = *(const float4*)&As[kk][ty * 8];
            float4 av1 = *(const float4*)&As[kk][ty * 8 + 4];
            float4 bv0 = *(const float4*)&Bs[kk][tx * 8];
            float4 bv1 = *(const float4*)&Bs[kk][tx * 8 + 4];
            float a_[8] = {av0.x, av0.y, av0.z, av0.w, av1.x, av1.y, av1.z, av1.w};
            float b_[8] = {bv0.x, bv0.y, bv0.z, bv0.w, bv1.x, bv1.y, bv1.z, bv1.w};
            #pragma unroll
            for (int i = 0; i < 8; ++i)
                #pragma unroll
                for (int j = 0; j < 8; ++j)
                    acc[i][j] = fmaf(a_[i], b_[j], acc[i][j]);
        }
    }

    #pragma unroll
    for (int i = 0; i < 8; ++i) {
        const int m = m0 + ty * 8 + i;
        const float bi = bias[m];
        float* yp = Y + ((size_t)b * H + m) * N1 + n0 + tx * 8;
        float4 v0 = make_float4(acc[i][0] + bi, acc[i][1] + bi, acc[i][2] + bi, acc[i][3] + bi);
        float4 v1 = make_float4(acc[i][4] + bi, acc[i][5] + bi, acc[i][6] + bi, acc[i][7] + bi);
        *(float4*)yp       = v0;
        *(float4*)(yp + 4) = v1;
    }
}

// ---------------- BN stats: one block per channel, deterministic reduction ----------------
__global__ __launch_bounds__(256)
void bn_stats_kernel(const float* __restrict__ Y, const float* __restrict__ g,
                     const float* __restrict__ be, float* __restrict__ scale,
                     float* __restrict__ shift) {
    const int c = blockIdx.x;
    const int tid = threadIdx.x;
    float s = 0.f, sq = 0.f;
    for (int b = 0; b < BATCH; ++b) {
        const float4* row = (const float4*)(Y + ((size_t)b * H + c) * N1);
        #pragma unroll
        for (int k = 0; k < N1 / 4; k += 256) {
            float4 v = row[k + tid];
            s  += v.x + v.y + v.z + v.w;
            sq += v.x * v.x + v.y * v.y + v.z * v.z + v.w * v.w;
        }
    }
    __shared__ float ss[256], sp[256];
    ss[tid] = s; sp[tid] = sq;
    __syncthreads();
    for (int o = 128; o > 0; o >>= 1) {
        if (tid < o) { ss[tid] += ss[tid + o]; sp[tid] += sp[tid + o]; }
        __syncthreads();
    }
    if (tid == 0) {
        const float inv = 1.0f / (float)(BATCH * N1);
        float mean = ss[0] * inv;
        float var  = sp[0] * inv - mean * mean;
        float sc = g[c] / sqrtf(var + BN_EPS);
        scale[c] = sc;
        shift[c] = be[c] - mean * sc;
    }
}

// ---------------- Final BN+ReLU ----------------
__global__ __launch_bounds__(256)
void bn_relu_kernel(const float* __restrict__ Yin, const float* __restrict__ scale,
                    const float* __restrict__ shift, float* __restrict__ out, int total4) {
    for (int i = blockIdx.x * blockDim.x + threadIdx.x; i < total4;
         i += gridDim.x * blockDim.x) {
        float4 v = ((const float4*)Yin)[i];
        const int c = (i >> 10) & 255;   // 4096 floats (=1024 float4) per channel row
        const float sc = scale[c], sh = shift[c];
        v.x = fmaxf(fmaf(v.x, sc, sh), 0.f);
        v.y = fmaxf(fmaf(v.y, sc, sh), 0.f);
        v.z = fmaxf(fmaf(v.z, sc, sh), 0.f);
        v.w = fmaxf(fmaf(v.w, sc, sh), 0.f);
        ((float4*)out)[i] = v;
    }
}

extern "C" void kernel_launch(void* const* d_in, const int* in_sizes, int n_in,
                              void* d_out, int out_size, void* d_ws, size_t ws_size,
                              hipStream_t stream) {
    const float* c1  = (const float*)d_in[0];
    const float* c2  = (const float*)d_in[1];
    const float* f1  = (const float*)d_in[2];
    const float* f2  = (const float*)d_in[3];
    const float* W1  = (const float*)d_in[4];
    const float* b1  = (const float*)d_in[5];
    const float* g1  = (const float*)d_in[6];
    const float* be1 = (const float*)d_in[7];
    const float* W2  = (const float*)d_in[8];
    const float* b2  = (const float*)d_in[9];
    const float* g2  = (const float*)d_in[10];
    const float* be2 = (const float*)d_in[11];
    float* out = (float*)d_out;

    // ws layout: F (interp, later reused as y2) | idx | w | bn params
    char* ws = (char*)d_ws;
    const size_t Fsize = (size_t)BATCH * C2 * N1;            // 16,777,216 floats = 64MB
    float* F    = (float*)ws;
    int*   idx  = (int*)(ws + Fsize * 4);
    float* w    = (float*)(ws + Fsize * 4 + (size_t)BATCH * N1 * 3 * 4);
    float* scale1 = (float*)(ws + Fsize * 4 + (size_t)BATCH * N1 * 3 * 8);
    float* shift1 = scale1 + 256;
    float* scale2 = shift1 + 256;
    float* shift2 = scale2 + 256;

    // 1) kNN (idx, w)
    knn_kernel<<<dim3(N1 / 256, BATCH), 256, 0, stream>>>(c1, c2, idx, w);
    // 2) interpolation -> F
    interp_kernel<<<dim3(N1 / 256, 4, BATCH), 256, 0, stream>>>(f2, idx, w, F);
    // 3) GEMM1: y1 = W1 @ concat(f1, F) + b1  -> d_out
    gemm_kernel<CIN, false><<<dim3(N1 / 128, H / 128, BATCH), 256, 0, stream>>>(
        W1, b1, f1, F, C1, (long)C1 * N1, (long)C2 * N1, nullptr, nullptr, out);
    // 4) BN1 stats
    bn_stats_kernel<<<H, 256, 0, stream>>>(out, g1, be1, scale1, shift1);
    // 5) GEMM2: y2 = W2 @ relu(bn1(y1)) + b2  -> F (reused)
    gemm_kernel<H, true><<<dim3(N1 / 128, H / 128, BATCH), 256, 0, stream>>>(
        W2, b2, out, nullptr, H, (long)H * N1, 0L, scale1, shift1, F);
    // 6) BN2 stats
    bn_stats_kernel<<<H, 256, 0, stream>>>(F, g2, be2, scale2, shift2);
    // 7) final BN2+ReLU -> d_out
    bn_relu_kernel<<<2048, 256, 0, stream>>>(F, scale2, shift2, out, (int)(Fsize / 4));
}

// Round 2
// 247.393 us; speedup vs baseline: 1.8337x; 1.8337x over previous
//
#include <hip/hip_runtime.h>
#include <math.h>

#define N1 4096
#define N2 1024
#define C1 128
#define C2 256
#define CIN 384
#define H 256
#define BATCH 16
#define BN_EPS 1e-5f

typedef __attribute__((ext_vector_type(8))) short bf16x8;
typedef __attribute__((ext_vector_type(4))) float f32x4;

__device__ inline float bf2f(short s) {
    union { unsigned u; float f; } x;
    x.u = ((unsigned)(unsigned short)s) << 16;
    return x.f;
}
__device__ inline short f2bf(float f) {
    union { float f; unsigned u; } x; x.f = f;
    unsigned r = x.u + 0x7fffu + ((x.u >> 16) & 1u);
    return (short)(r >> 16);
}

// ---------------- KNN: 3 nearest neighbors + inverse-distance weights ----------------
__global__ __launch_bounds__(256)
void knn_kernel(const float* __restrict__ c1, const float* __restrict__ c2,
                int* __restrict__ idx_out, float* __restrict__ w_out) {
    __shared__ float sx[N2], sy[N2], sz[N2], sq[N2];
    const int b = blockIdx.y;
    const float* c2b = c2 + (size_t)b * 3 * N2;
    for (int j = threadIdx.x; j < N2; j += blockDim.x) {
        float x = c2b[j], y = c2b[N2 + j], z = c2b[2 * N2 + j];
        sx[j] = x; sy[j] = y; sz[j] = z;
        sq[j] = x * x + y * y + z * z;
    }
    __syncthreads();

    const int n = blockIdx.x * blockDim.x + threadIdx.x;
    const float* c1b = c1 + (size_t)b * 3 * N1;
    const float x = c1b[n], y = c1b[N1 + n], z = c1b[2 * N1 + n];
    const float s1 = x * x + y * y + z * z;

    float d0 = 3.4e38f, d1 = 3.4e38f, d2 = 3.4e38f;
    int i0 = 0, i1 = 0, i2 = 0;
    #pragma unroll 4
    for (int j = 0; j < N2; ++j) {
        float dot = x * sx[j] + y * sy[j] + z * sz[j];
        float d = s1 + sq[j] - 2.0f * dot;
        if (d < d2) {
            if (d < d1) {
                d2 = d1; i2 = i1;
                if (d < d0) { d1 = d0; i1 = i0; d0 = d; i0 = j; }
                else        { d1 = d;  i1 = j; }
            } else { d2 = d; i2 = j; }
        }
    }
    float r0 = 1.0f / (d0 + 1e-8f);
    float r1 = 1.0f / (d1 + 1e-8f);
    float r2 = 1.0f / (d2 + 1e-8f);
    float rs = r0 + r1 + r2;
    size_t base = ((size_t)b * N1 + n) * 3;
    idx_out[base + 0] = i0; idx_out[base + 1] = i1; idx_out[base + 2] = i2;
    w_out[base + 0] = r0 / rs; w_out[base + 1] = r1 / rs; w_out[base + 2] = r2 / rs;
}

// ---------------- Interpolation -> bf16 F ----------------
__global__ __launch_bounds__(256)
void interp_kernel(const float* __restrict__ f2, const int* __restrict__ idx,
                   const float* __restrict__ w, short* __restrict__ F) {
    const int b = blockIdx.z;
    const int c0 = blockIdx.y * 64;
    const int n = blockIdx.x * blockDim.x + threadIdx.x;
    size_t base = ((size_t)b * N1 + n) * 3;
    const int i0 = idx[base], i1 = idx[base + 1], i2 = idx[base + 2];
    const float w0 = w[base], w1 = w[base + 1], w2 = w[base + 2];
    const float* f2b = f2 + (size_t)b * C2 * N2;
    short* Fb = F + (size_t)b * C2 * N1;
    #pragma unroll 4
    for (int c = c0; c < c0 + 64; ++c) {
        const float* row = f2b + (size_t)c * N2;
        Fb[(size_t)c * N1 + n] = f2bf(w0 * row[i0] + w1 * row[i1] + w2 * row[i2]);
    }
}

// ---------------- Prep: W [256][K] f32 -> swizzled bf16 [K/8][256][8] ----------------
__global__ __launch_bounds__(256)
void prep_w(const float* __restrict__ W, short* __restrict__ Wsw, int K) {
    const int nkb = K >> 3;
    const int id = blockIdx.x * 256 + threadIdx.x;
    if (id >= 256 * nkb) return;
    const int m = id / nkb, kb = id % nkb;
    const float* src = W + (size_t)m * K + kb * 8;
    bf16x8 v;
    #pragma unroll
    for (int j = 0; j < 8; ++j) v[j] = f2bf(src[j]);
    *(bf16x8*)(Wsw + ((size_t)kb * 256 + m) * 8) = v;
}

// ---------------- MFMA GEMM: Y[b][m][n] (bf16) = W @ X ----------------
// MODE 0: K=384, B rows [0,128) from f32 X0 (f1), rows [128,384) from bf16 X1 (F). No BN.
// MODE 1: K=256, B rows from bf16 X1 (y1), BN(scale,shift)+ReLU applied on load.
template<int MODE>
__global__ __launch_bounds__(512)
void gemm_kernel(const short* __restrict__ Wsw,
                 const float* __restrict__ X0, const short* __restrict__ X1,
                 const float* __restrict__ scale, const float* __restrict__ shift,
                 short* __restrict__ Y) {
    constexpr int K = (MODE == 0) ? CIN : H;
    constexpr int NT = K / 32;

    __shared__ __align__(16) short A_lds[2][4][256][8];  // 32KB
    __shared__ __align__(16) short B_lds[2][4][128][8];  // 16KB
    __shared__ float sc_s[256], sh_s[256];

    const int t = threadIdx.x;
    const int n0 = blockIdx.x * 128;
    const int b  = blockIdx.y;

    if (MODE == 1) {
        if (t < 256) { sc_s[t] = scale[t]; sh_s[t] = shift[t]; }
    }

    const float* X0b = (MODE == 0) ? (X0 + (size_t)b * C1 * N1) : (const float*)nullptr;
    const short* X1b = X1 + (size_t)b * 256 * N1;

    const int sn  = t & 127;   // B-staging: n within tile
    const int skb = t >> 7;    // B-staging: k-chunk 0..3

    const int lane = t & 63;
    const int wv = t >> 6;
    const int wm = wv >> 1, wn = wv & 1;
    const int l16 = lane & 15, lq = lane >> 4;
    const int am_base = wm * 64 + l16;
    const int bn_base = wn * 64 + l16;

    f32x4 acc[4][4];
    #pragma unroll
    for (int i = 0; i < 4; ++i)
        #pragma unroll
        for (int j = 0; j < 4; ++j)
            acc[i][j] = (f32x4){0.f, 0.f, 0.f, 0.f};

    auto stageA = [&](int step, int bufi) {
        #pragma unroll
        for (int i = 0; i < 2; ++i) {
            const int slot = i * 512 + t;       // 0..1023
            const int kbl = slot >> 8;          // 0..3
            const int m   = slot & 255;
            const short* g = Wsw + ((size_t)(step * 4 + kbl) * 256 + m) * 8;
            *(bf16x8*)&A_lds[bufi][kbl][m][0] = *(const bf16x8*)g;
        }
    };

    auto stageB = [&](int step, int bufi) {
        const int gk = step * 32 + skb * 8;
        bf16x8 pv;
        if (MODE == 0 && gk < C1) {
            const float* src = X0b + (size_t)gk * N1 + n0 + sn;
            #pragma unroll
            for (int j = 0; j < 8; ++j) pv[j] = f2bf(src[(size_t)j * N1]);
        } else if (MODE == 0) {
            const short* src = X1b + (size_t)(gk - C1) * N1 + n0 + sn;
            #pragma unroll
            for (int j = 0; j < 8; ++j) pv[j] = src[(size_t)j * N1];
        } else {
            const short* src = X1b + (size_t)gk * N1 + n0 + sn;
            #pragma unroll
            for (int j = 0; j < 8; ++j) {
                float x = bf2f(src[(size_t)j * N1]);
                x = fmaxf(fmaf(x, sc_s[gk + j], sh_s[gk + j]), 0.f);
                pv[j] = f2bf(x);
            }
        }
        *(bf16x8*)&B_lds[bufi][skb][sn][0] = pv;
    };

    auto compute = [&](int bufi) {
        bf16x8 a[4], bb[4];
        #pragma unroll
        for (int f = 0; f < 4; ++f) {
            a[f]  = *(const bf16x8*)&A_lds[bufi][lq][am_base + f * 16][0];
            bb[f] = *(const bf16x8*)&B_lds[bufi][lq][bn_base + f * 16][0];
        }
        #pragma unroll
        for (int i = 0; i < 4; ++i)
            #pragma unroll
            for (int j = 0; j < 4; ++j)
                acc[i][j] = __builtin_amdgcn_mfma_f32_16x16x32_bf16(a[i], bb[j], acc[i][j], 0, 0, 0);
    };

    __syncthreads();   // sc_s ready (and uniform start)
    stageA(0, 0); stageB(0, 0);
    int buf = 0;
    for (int s = 0; s < NT; ++s) {
        __syncthreads();
        if (s + 1 < NT) { stageA(s + 1, buf ^ 1); stageB(s + 1, buf ^ 1); }
        compute(buf);
        buf ^= 1;
    }

    // epilogue: C row = (lane>>4)*4 + reg, col = lane&15  [m89-verified layout]
    short* Yb = Y + (size_t)b * H * N1;
    #pragma unroll
    for (int i = 0; i < 4; ++i) {
        const int m = wm * 64 + i * 16 + lq * 4;
        #pragma unroll
        for (int j = 0; j < 4; ++j) {
            const int n = n0 + wn * 64 + j * 16 + l16;
            short* yp = Yb + (size_t)m * N1 + n;
            #pragma unroll
            for (int r = 0; r < 4; ++r)
                yp[(size_t)r * N1] = f2bf(acc[i][j][r]);
        }
    }
}

// ---------------- BN stats from bf16 y ----------------
__global__ __launch_bounds__(256)
void bn_stats(const short* __restrict__ Y, const float* __restrict__ g,
              const float* __restrict__ be, float* __restrict__ scale,
              float* __restrict__ shift) {
    const int c = blockIdx.x;
    const int tid = threadIdx.x;
    float s = 0.f, sq = 0.f;
    for (int b = 0; b < BATCH; ++b) {
        const bf16x8* row = (const bf16x8*)(Y + ((size_t)b * H + c) * N1);
        for (int k = tid; k < N1 / 8; k += 256) {
            bf16x8 v = row[k];
            #pragma unroll
            for (int e = 0; e < 8; ++e) { float x = bf2f(v[e]); s += x; sq += x * x; }
        }
    }
    __shared__ float ss[256], sp[256];
    ss[tid] = s; sp[tid] = sq;
    __syncthreads();
    for (int o = 128; o > 0; o >>= 1) {
        if (tid < o) { ss[tid] += ss[tid + o]; sp[tid] += sp[tid + o]; }
        __syncthreads();
    }
    if (tid == 0) {
        const float inv = 1.0f / (float)(BATCH * N1);
        float mean = ss[0] * inv;
        float var  = sp[0] * inv - mean * mean;
        float sc = g[c] / sqrtf(var + BN_EPS);
        scale[c] = sc;
        shift[c] = be[c] - mean * sc;
    }
}

// ---------------- Final BN2+ReLU: bf16 y2 -> f32 out ----------------
__global__ __launch_bounds__(256)
void final_bn_relu(const short* __restrict__ Y, const float* __restrict__ scale,
                   const float* __restrict__ shift, float* __restrict__ out) {
    const int i8 = blockIdx.x * 256 + threadIdx.x;   // 2M vec8 groups
    bf16x8 v = ((const bf16x8*)Y)[i8];
    const int c = (i8 >> 9) & 255;                   // 512 vec8 per channel-row
    const float sc = scale[c], sh = shift[c];
    float o[8];
    #pragma unroll
    for (int e = 0; e < 8; ++e)
        o[e] = fmaxf(fmaf(bf2f(v[e]), sc, sh), 0.f);
    float4* op = (float4*)out + (size_t)i8 * 2;
    op[0] = make_float4(o[0], o[1], o[2], o[3]);
    op[1] = make_float4(o[4], o[5], o[6], o[7]);
}

extern "C" void kernel_launch(void* const* d_in, const int* in_sizes, int n_in,
                              void* d_out, int out_size, void* d_ws, size_t ws_size,
                              hipStream_t stream) {
    const float* c1  = (const float*)d_in[0];
    const float* c2  = (const float*)d_in[1];
    const float* f1  = (const float*)d_in[2];
    const float* f2  = (const float*)d_in[3];
    const float* W1  = (const float*)d_in[4];
    const float* g1  = (const float*)d_in[6];
    const float* be1 = (const float*)d_in[7];
    const float* W2  = (const float*)d_in[8];
    const float* g2  = (const float*)d_in[10];
    const float* be2 = (const float*)d_in[11];
    float* out = (float*)d_out;

    // workspace layout
    char* ws = (char*)d_ws;
    size_t off = 0;
    short* F   = (short*)(ws + off); off += (size_t)BATCH * C2 * N1 * 2;  // 32MB (interp; reused as y2)
    short* y1  = (short*)(ws + off); off += (size_t)BATCH * H * N1 * 2;   // 32MB
    short* W1s = (short*)(ws + off); off += (size_t)CIN * H * 2;          // 192KB
    short* W2s = (short*)(ws + off); off += (size_t)H * H * 2;            // 128KB
    int*   idx = (int*)(ws + off);   off += (size_t)BATCH * N1 * 3 * 4;
    float* wgt = (float*)(ws + off); off += (size_t)BATCH * N1 * 3 * 4;
    float* scale1 = (float*)(ws + off); off += 1024;
    float* shift1 = (float*)(ws + off); off += 1024;
    float* scale2 = (float*)(ws + off); off += 1024;
    float* shift2 = (float*)(ws + off); off += 1024;

    // weight pre-swizzle (bf16, k-chunked)
    prep_w<<<(256 * (CIN / 8) + 255) / 256, 256, 0, stream>>>(W1, W1s, CIN);
    prep_w<<<(256 * (H / 8) + 255) / 256, 256, 0, stream>>>(W2, W2s, H);
    // kNN + interpolation
    knn_kernel<<<dim3(N1 / 256, BATCH), 256, 0, stream>>>(c1, c2, idx, wgt);
    interp_kernel<<<dim3(N1 / 256, 4, BATCH), 256, 0, stream>>>(f2, idx, wgt, F);
    // GEMM1 -> y1 (bf16, pre-BN)
    gemm_kernel<0><<<dim3(N1 / 128, BATCH), 512, 0, stream>>>(
        W1s, f1, F, nullptr, nullptr, y1);
    bn_stats<<<H, 256, 0, stream>>>(y1, g1, be1, scale1, shift1);
    // GEMM2 (BN1+ReLU fused on load) -> y2 (reuses F buffer)
    gemm_kernel<1><<<dim3(N1 / 128, BATCH), 512, 0, stream>>>(
        W2s, nullptr, y1, scale1, shift1, F);
    bn_stats<<<H, 256, 0, stream>>>(F, g2, be2, scale2, shift2);
    // final BN2+ReLU -> f32 out
    final_bn_relu<<<(BATCH * H * N1 / 8 + 255) / 256, 256, 0, stream>>>(F, scale2, shift2, out);
}

// Round 4
// 172.797 us; speedup vs baseline: 2.6253x; 1.4317x over previous
//
#include <hip/hip_runtime.h>
#include <math.h>

#define N1 4096
#define N2 1024
#define C1 128
#define C2 256
#define CIN 384
#define H 256
#define BATCH 16
#define BN_EPS 1e-5f

typedef __attribute__((ext_vector_type(8))) short bf16x8;
typedef __attribute__((ext_vector_type(4))) float f32x4;

__device__ inline float bf2f(short s) {
    union { unsigned u; float f; } x;
    x.u = ((unsigned)(unsigned short)s) << 16;
    return x.f;
}
__device__ inline short f2bf(float f) {
    union { float f; unsigned u; } x; x.f = f;
    unsigned r = x.u + 0x7fffu + ((x.u >> 16) & 1u);
    return (short)(r >> 16);
}

// ---------------- KNN v3: exact branchless top-3, 4-way candidate split ----------------
// Grid: (N1/64, BATCH), 256 threads. Wave w scans candidate quarter w for 64 queries
// (lane = query). Full-precision (d, idx) carried; stable strict-< insert matches
// lax.top_k tie-breaking (lower index first). No key truncation (round-3 bug).
__global__ __launch_bounds__(256)
void knn_kernel(const float* __restrict__ c1, const float* __restrict__ c2,
                int* __restrict__ idx_out, float* __restrict__ w_out) {
    __shared__ __align__(16) float4 sc[N2];     // (x,y,z,|c2|^2) 16KB
    __shared__ float md[64 * 13];               // stride 13: no bank conflicts
    __shared__ int   mi[64 * 13];
    const int b = blockIdx.y;
    const float* c2b = c2 + (size_t)b * 3 * N2;
    for (int j = threadIdx.x; j < N2; j += 256) {
        float xx = c2b[j], yy = c2b[N2 + j], zz = c2b[2 * N2 + j];
        sc[j] = make_float4(xx, yy, zz, xx * xx + yy * yy + zz * zz);
    }
    __syncthreads();

    const int t = threadIdx.x;
    const int q = t & 63;
    const int quarter = t >> 6;
    const int n = blockIdx.x * 64 + q;
    const float* c1b = c1 + (size_t)b * 3 * N1;
    const float x = c1b[n], y = c1b[N1 + n], z = c1b[2 * N1 + n];
    const float s1 = x * x + y * y + z * z;

    float d0 = 3.4e38f, d1 = 3.4e38f, d2 = 3.4e38f;
    int i0 = 0, i1 = 0, i2 = 0;
    const int j0 = quarter * 256;
    #pragma unroll 4
    for (int jj = 0; jj < 256; ++jj) {
        const int j = j0 + jj;
        float4 cc = sc[j];                       // wave-uniform -> LDS broadcast
        float dot = x * cc.x + y * cc.y + z * cc.z;
        float d = s1 + cc.w - 2.0f * dot;        // same arithmetic as round-2 (passed)
        bool c0 = d < d0, c1v = d < d1, c2v = d < d2;
        d2 = c1v ? d1 : (c2v ? d : d2);  i2 = c1v ? i1 : (c2v ? j : i2);
        d1 = c0 ? d0 : (c1v ? d : d1);   i1 = c0 ? i0 : (c1v ? j : i1);
        d0 = c0 ? d  : d0;               i0 = c0 ? j  : i0;
    }
    const int mb = q * 13 + quarter * 3;
    md[mb + 0] = d0; md[mb + 1] = d1; md[mb + 2] = d2;
    mi[mb + 0] = i0; mi[mb + 1] = i1; mi[mb + 2] = i2;
    __syncthreads();

    if (t < 64) {
        // merge the 4 quarters' top-3 lists (quarter-ascending = index-ascending,
        // so stable strict-< insert keeps lax.top_k tie order)
        float e0 = 3.4e38f, e1 = 3.4e38f, e2 = 3.4e38f;
        int a0 = 0, a1 = 0, a2 = 0;
        #pragma unroll
        for (int r = 0; r < 12; ++r) {
            const int rr = t * 13 + (r / 3) * 3 + (r % 3);
            float d = md[rr]; int j = mi[rr];
            bool c0 = d < e0, c1v = d < e1, c2v = d < e2;
            e2 = c1v ? e1 : (c2v ? d : e2);  a2 = c1v ? a1 : (c2v ? j : a2);
            e1 = c0 ? e0 : (c1v ? d : e1);   a1 = c0 ? a0 : (c1v ? j : a1);
            e0 = c0 ? d  : e0;               a0 = c0 ? j  : a0;
        }
        float r0 = 1.0f / (e0 + 1e-8f);
        float r1 = 1.0f / (e1 + 1e-8f);
        float r2 = 1.0f / (e2 + 1e-8f);
        float rs = r0 + r1 + r2;
        size_t base = ((size_t)b * N1 + n) * 3;
        idx_out[base + 0] = a0; idx_out[base + 1] = a1; idx_out[base + 2] = a2;
        w_out[base + 0] = r0 / rs; w_out[base + 1] = r1 / rs; w_out[base + 2] = r2 / rs;
    }
}

// ---------------- Prep: W [256][K] f32 -> swizzled bf16 [K/8][256][8] ----------------
__global__ __launch_bounds__(256)
void prep_w(const float* __restrict__ W, short* __restrict__ Wsw, int K) {
    const int nkb = K >> 3;
    const int id = blockIdx.x * 256 + threadIdx.x;
    if (id >= 256 * nkb) return;
    const int m = id / nkb, kb = id % nkb;
    const float* src = W + (size_t)m * K + kb * 8;
    bf16x8 v;
    #pragma unroll
    for (int j = 0; j < 8; ++j) v[j] = f2bf(src[j]);
    *(bf16x8*)(Wsw + ((size_t)kb * 256 + m) * 8) = v;
}

// ---------------- MFMA GEMM: Y[b][m][n] (bf16) = W @ X ----------------
// MODE 0: K=384. B rows [0,128) from f32 X0 (f1); rows [128,384) interpolated on the
//         fly from f2 via per-column (idx,w) — the interp kernel is fused here.
// MODE 1: K=256. B rows from bf16 X1 (y1), BN(scale,shift)+ReLU applied on load.
template<int MODE>
__global__ __launch_bounds__(512)
void gemm_kernel(const short* __restrict__ Wsw,
                 const float* __restrict__ X0, const short* __restrict__ X1,
                 const float* __restrict__ f2, const int* __restrict__ idxp,
                 const float* __restrict__ wp,
                 const float* __restrict__ scale, const float* __restrict__ shift,
                 short* __restrict__ Y) {
    constexpr int K = (MODE == 0) ? CIN : H;
    constexpr int NT = K / 32;

    __shared__ __align__(16) short A_lds[2][4][256][8];  // 32KB
    __shared__ __align__(16) short B_lds[2][4][128][8];  // 16KB
    __shared__ float sc_s[256], sh_s[256];

    const int t = threadIdx.x;
    const int n0 = blockIdx.x * 128;
    const int b  = blockIdx.y;

    if (MODE == 1) {
        if (t < 256) { sc_s[t] = scale[t]; sh_s[t] = shift[t]; }
    }

    const int sn  = t & 127;   // B-staging: n within tile
    const int skb = t >> 7;    // B-staging: k-chunk 0..3

    const float* X0b = (MODE == 0) ? (X0 + (size_t)b * C1 * N1) : (const float*)nullptr;
    const short* X1b = (MODE == 1) ? (X1 + (size_t)b * H * N1) : (const short*)nullptr;

    // fused-interp state (MODE 0): column n0+sn is fixed for the whole K loop
    const float* f2b = nullptr;
    int gi0 = 0, gi1 = 0, gi2 = 0;
    float gw0 = 0.f, gw1 = 0.f, gw2 = 0.f;
    if (MODE == 0) {
        f2b = f2 + (size_t)b * C2 * N2;
        size_t ibase = ((size_t)b * N1 + n0 + sn) * 3;
        gi0 = idxp[ibase]; gi1 = idxp[ibase + 1]; gi2 = idxp[ibase + 2];
        gw0 = wp[ibase];   gw1 = wp[ibase + 1];   gw2 = wp[ibase + 2];
    }

    const int lane = t & 63;
    const int wv = t >> 6;
    const int wm = wv >> 1, wn = wv & 1;
    const int l16 = lane & 15, lq = lane >> 4;
    const int am_base = wm * 64 + l16;
    const int bn_base = wn * 64 + l16;

    f32x4 acc[4][4];
    #pragma unroll
    for (int i = 0; i < 4; ++i)
        #pragma unroll
        for (int j = 0; j < 4; ++j)
            acc[i][j] = (f32x4){0.f, 0.f, 0.f, 0.f};

    auto stageA = [&](int step, int bufi) {
        #pragma unroll
        for (int i = 0; i < 2; ++i) {
            const int slot = i * 512 + t;       // 0..1023
            const int kbl = slot >> 8;          // 0..3
            const int m   = slot & 255;
            const short* g = Wsw + ((size_t)(step * 4 + kbl) * 256 + m) * 8;
            *(bf16x8*)&A_lds[bufi][kbl][m][0] = *(const bf16x8*)g;
        }
    };

    auto stageB = [&](int step, int bufi) {
        const int gk = step * 32 + skb * 8;
        bf16x8 pv;
        if (MODE == 0 && gk < C1) {
            const float* src = X0b + (size_t)gk * N1 + n0 + sn;
            #pragma unroll
            for (int j = 0; j < 8; ++j) pv[j] = f2bf(src[(size_t)j * N1]);
        } else if (MODE == 0) {
            const float* p = f2b + (size_t)(gk - C1) * N2;
            #pragma unroll
            for (int j = 0; j < 8; ++j) {
                float v = gw0 * p[gi0] + gw1 * p[gi1] + gw2 * p[gi2];
                pv[j] = f2bf(v);
                p += N2;
            }
        } else {
            const short* src = X1b + (size_t)gk * N1 + n0 + sn;
            #pragma unroll
            for (int j = 0; j < 8; ++j) {
                float x = bf2f(src[(size_t)j * N1]);
                x = fmaxf(fmaf(x, sc_s[gk + j], sh_s[gk + j]), 0.f);
                pv[j] = f2bf(x);
            }
        }
        *(bf16x8*)&B_lds[bufi][skb][sn][0] = pv;
    };

    auto compute = [&](int bufi) {
        bf16x8 a[4], bb[4];
        #pragma unroll
        for (int f = 0; f < 4; ++f) {
            a[f]  = *(const bf16x8*)&A_lds[bufi][lq][am_base + f * 16][0];
            bb[f] = *(const bf16x8*)&B_lds[bufi][lq][bn_base + f * 16][0];
        }
        #pragma unroll
        for (int i = 0; i < 4; ++i)
            #pragma unroll
            for (int j = 0; j < 4; ++j)
                acc[i][j] = __builtin_amdgcn_mfma_f32_16x16x32_bf16(a[i], bb[j], acc[i][j], 0, 0, 0);
    };

    __syncthreads();   // sc_s ready (and uniform start)
    stageA(0, 0); stageB(0, 0);
    int buf = 0;
    for (int s = 0; s < NT; ++s) {
        __syncthreads();
        if (s + 1 < NT) { stageA(s + 1, buf ^ 1); stageB(s + 1, buf ^ 1); }
        compute(buf);
        buf ^= 1;
    }

    // epilogue: C row = (lane>>4)*4 + reg, col = lane&15  [m89-verified layout]
    short* Yb = Y + (size_t)b * H * N1;
    #pragma unroll
    for (int i = 0; i < 4; ++i) {
        const int m = wm * 64 + i * 16 + lq * 4;
        #pragma unroll
        for (int j = 0; j < 4; ++j) {
            const int n = n0 + wn * 64 + j * 16 + l16;
            short* yp = Yb + (size_t)m * N1 + n;
            #pragma unroll
            for (int r = 0; r < 4; ++r)
                yp[(size_t)r * N1] = f2bf(acc[i][j][r]);
        }
    }
}

// ---------------- BN stats from bf16 y ----------------
__global__ __launch_bounds__(256)
void bn_stats(const short* __restrict__ Y, const float* __restrict__ g,
              const float* __restrict__ be, float* __restrict__ scale,
              float* __restrict__ shift) {
    const int c = blockIdx.x;
    const int tid = threadIdx.x;
    float s = 0.f, sq = 0.f;
    for (int b = 0; b < BATCH; ++b) {
        const bf16x8* row = (const bf16x8*)(Y + ((size_t)b * H + c) * N1);
        for (int k = tid; k < N1 / 8; k += 256) {
            bf16x8 v = row[k];
            #pragma unroll
            for (int e = 0; e < 8; ++e) { float x = bf2f(v[e]); s += x; sq += x * x; }
        }
    }
    __shared__ float ss[256], sp[256];
    ss[tid] = s; sp[tid] = sq;
    __syncthreads();
    for (int o = 128; o > 0; o >>= 1) {
        if (tid < o) { ss[tid] += ss[tid + o]; sp[tid] += sp[tid + o]; }
        __syncthreads();
    }
    if (tid == 0) {
        const float inv = 1.0f / (float)(BATCH * N1);
        float mean = ss[0] * inv;
        float var  = sp[0] * inv - mean * mean;
        float sc = g[c] / sqrtf(var + BN_EPS);
        scale[c] = sc;
        shift[c] = be[c] - mean * sc;
    }
}

// ---------------- Final BN2+ReLU: bf16 y2 -> f32 out ----------------
__global__ __launch_bounds__(256)
void final_bn_relu(const short* __restrict__ Y, const float* __restrict__ scale,
                   const float* __restrict__ shift, float* __restrict__ out) {
    const int i8 = blockIdx.x * 256 + threadIdx.x;   // 2M vec8 groups
    bf16x8 v = ((const bf16x8*)Y)[i8];
    const int c = (i8 >> 9) & 255;                   // 512 vec8 per channel-row
    const float sc = scale[c], sh = shift[c];
    float o[8];
    #pragma unroll
    for (int e = 0; e < 8; ++e)
        o[e] = fmaxf(fmaf(bf2f(v[e]), sc, sh), 0.f);
    float4* op = (float4*)out + (size_t)i8 * 2;
    op[0] = make_float4(o[0], o[1], o[2], o[3]);
    op[1] = make_float4(o[4], o[5], o[6], o[7]);
}

extern "C" void kernel_launch(void* const* d_in, const int* in_sizes, int n_in,
                              void* d_out, int out_size, void* d_ws, size_t ws_size,
                              hipStream_t stream) {
    const float* c1  = (const float*)d_in[0];
    const float* c2  = (const float*)d_in[1];
    const float* f1  = (const float*)d_in[2];
    const float* f2  = (const float*)d_in[3];
    const float* W1  = (const float*)d_in[4];
    const float* g1  = (const float*)d_in[6];
    const float* be1 = (const float*)d_in[7];
    const float* W2  = (const float*)d_in[8];
    const float* g2  = (const float*)d_in[10];
    const float* be2 = (const float*)d_in[11];
    float* out = (float*)d_out;

    // workspace layout
    char* ws = (char*)d_ws;
    size_t off = 0;
    short* y2  = (short*)(ws + off); off += (size_t)BATCH * H * N1 * 2;   // 32MB
    short* y1  = (short*)(ws + off); off += (size_t)BATCH * H * N1 * 2;   // 32MB
    short* W1s = (short*)(ws + off); off += (size_t)CIN * H * 2;          // 192KB
    short* W2s = (short*)(ws + off); off += (size_t)H * H * 2;            // 128KB
    int*   idx = (int*)(ws + off);   off += (size_t)BATCH * N1 * 3 * 4;
    float* wgt = (float*)(ws + off); off += (size_t)BATCH * N1 * 3 * 4;
    float* scale1 = (float*)(ws + off); off += 1024;
    float* shift1 = (float*)(ws + off); off += 1024;
    float* scale2 = (float*)(ws + off); off += 1024;
    float* shift2 = (float*)(ws + off); off += 1024;

    // weight pre-swizzle (bf16, k-chunked)
    prep_w<<<(256 * (CIN / 8) + 255) / 256, 256, 0, stream>>>(W1, W1s, CIN);
    prep_w<<<(256 * (H / 8) + 255) / 256, 256, 0, stream>>>(W2, W2s, H);
    // kNN (idx, weights)
    knn_kernel<<<dim3(N1 / 64, BATCH), 256, 0, stream>>>(c1, c2, idx, wgt);
    // GEMM1 (interp fused into B-staging) -> y1 (bf16, pre-BN)
    gemm_kernel<0><<<dim3(N1 / 128, BATCH), 512, 0, stream>>>(
        W1s, f1, nullptr, f2, idx, wgt, nullptr, nullptr, y1);
    bn_stats<<<H, 256, 0, stream>>>(y1, g1, be1, scale1, shift1);
    // GEMM2 (BN1+ReLU fused on load) -> y2
    gemm_kernel<1><<<dim3(N1 / 128, BATCH), 512, 0, stream>>>(
        W2s, nullptr, y1, nullptr, nullptr, nullptr, scale1, shift1, y2);
    bn_stats<<<H, 256, 0, stream>>>(y2, g2, be2, scale2, shift2);
    // final BN2+ReLU -> f32 out
    final_bn_relu<<<(BATCH * H * N1 / 8 + 255) / 256, 256, 0, stream>>>(y2, scale2, shift2, out);
}

// Round 5
// 148.789 us; speedup vs baseline: 3.0489x; 1.1614x over previous
//
#include <hip/hip_runtime.h>
#include <math.h>

#define N1 4096
#define N2 1024
#define C1 128
#define C2 256
#define CIN 384
#define H 256
#define BATCH 16
#define BN_EPS 1e-5f

typedef __attribute__((ext_vector_type(8))) short bf16x8;
typedef __attribute__((ext_vector_type(4))) float f32x4;

__device__ inline float bf2f(short s) {
    union { unsigned u; float f; } x;
    x.u = ((unsigned)(unsigned short)s) << 16;
    return x.f;
}
__device__ inline short f2bf(float f) {
    union { float f; unsigned u; } x; x.f = f;
    unsigned r = x.u + 0x7fffu + ((x.u >> 16) & 1u);
    return (short)(r >> 16);
}

typedef const __attribute__((address_space(1))) unsigned int guint;
typedef __attribute__((address_space(3))) unsigned int luint;
__device__ inline void gll16(const void* g, void* l) {
    __builtin_amdgcn_global_load_lds((guint*)g, (luint*)l, 16, 0, 0);
}

// ---------------- KNN: exact branchless top-3, packed (idx,w) output ----------------
__global__ __launch_bounds__(256)
void knn_kernel(const float* __restrict__ c1, const float* __restrict__ c2,
                float4* __restrict__ pk) {
    __shared__ __align__(16) float4 sc[N2];
    __shared__ float md[64 * 13];
    __shared__ int   mi[64 * 13];
    const int b = blockIdx.y;
    const float* c2b = c2 + (size_t)b * 3 * N2;
    for (int j = threadIdx.x; j < N2; j += 256) {
        float xx = c2b[j], yy = c2b[N2 + j], zz = c2b[2 * N2 + j];
        sc[j] = make_float4(xx, yy, zz, xx * xx + yy * yy + zz * zz);
    }
    __syncthreads();

    const int t = threadIdx.x;
    const int q = t & 63;
    const int quarter = t >> 6;
    const int n = blockIdx.x * 64 + q;
    const float* c1b = c1 + (size_t)b * 3 * N1;
    const float x = c1b[n], y = c1b[N1 + n], z = c1b[2 * N1 + n];
    const float s1 = x * x + y * y + z * z;

    float d0 = 3.4e38f, d1 = 3.4e38f, d2 = 3.4e38f;
    int i0 = 0, i1 = 0, i2 = 0;
    const int j0 = quarter * 256;
    #pragma unroll 4
    for (int jj = 0; jj < 256; ++jj) {
        const int j = j0 + jj;
        float4 cc = sc[j];
        float dot = x * cc.x + y * cc.y + z * cc.z;
        float d = s1 + cc.w - 2.0f * dot;
        bool c0 = d < d0, c1v = d < d1, c2v = d < d2;
        d2 = c1v ? d1 : (c2v ? d : d2);  i2 = c1v ? i1 : (c2v ? j : i2);
        d1 = c0 ? d0 : (c1v ? d : d1);   i1 = c0 ? i0 : (c1v ? j : i1);
        d0 = c0 ? d  : d0;               i0 = c0 ? j  : i0;
    }
    const int mb = q * 13 + quarter * 3;
    md[mb + 0] = d0; md[mb + 1] = d1; md[mb + 2] = d2;
    mi[mb + 0] = i0; mi[mb + 1] = i1; mi[mb + 2] = i2;
    __syncthreads();

    if (t < 64) {
        float e0 = 3.4e38f, e1 = 3.4e38f, e2 = 3.4e38f;
        int a0 = 0, a1 = 0, a2 = 0;
        #pragma unroll
        for (int r = 0; r < 12; ++r) {
            const int rr = t * 13 + (r / 3) * 3 + (r % 3);
            float d = md[rr]; int j = mi[rr];
            bool c0 = d < e0, c1v = d < e1, c2v = d < e2;
            e2 = c1v ? e1 : (c2v ? d : e2);  a2 = c1v ? a1 : (c2v ? j : a2);
            e1 = c0 ? e0 : (c1v ? d : e1);   a1 = c0 ? a0 : (c1v ? j : a1);
            e0 = c0 ? d  : e0;               a0 = c0 ? j  : a0;
        }
        float r0 = 1.0f / (e0 + 1e-8f);
        float r1 = 1.0f / (e1 + 1e-8f);
        float r2 = 1.0f / (e2 + 1e-8f);
        float rs = r0 + r1 + r2;
        unsigned pack = (unsigned)a0 | ((unsigned)a1 << 10) | ((unsigned)a2 << 20);
        pk[(size_t)b * N1 + n] = make_float4(__uint_as_float(pack), r0 / rs, r1 / rs, r2 / rs);
    }
}

// ---------------- Prep: W [256][K] f32 -> swizzled bf16 [K/8][256][8] ----------------
__global__ __launch_bounds__(256)
void prep_w(const float* __restrict__ W, short* __restrict__ Wsw, int K) {
    const int nkb = K >> 3;
    const int id = blockIdx.x * 256 + threadIdx.x;
    if (id >= 256 * nkb) return;
    const int m = id / nkb, kb = id % nkb;
    const float* src = W + (size_t)m * K + kb * 8;
    bf16x8 v;
    #pragma unroll
    for (int j = 0; j < 8; ++j) v[j] = f2bf(src[j]);
    *(bf16x8*)(Wsw + ((size_t)kb * 256 + m) * 8) = v;
}

// ---------------- Transpose f2 [b][c][j] f32 -> f2t [b][j][c] bf16 ----------------
__global__ __launch_bounds__(256)
void transpose_f2(const float* __restrict__ f2, short* __restrict__ f2t) {
    __shared__ float st[32][33];
    const int j0 = blockIdx.x * 32, c0 = blockIdx.y * 32, b = blockIdx.z;
    const int t = threadIdx.x;
    {
        const int cc = t >> 3, jj = (t & 7) * 4;
        const float* src = f2 + ((size_t)b * C2 + c0 + cc) * N2 + j0 + jj;
        float4 v = *(const float4*)src;
        st[cc][jj + 0] = v.x; st[cc][jj + 1] = v.y;
        st[cc][jj + 2] = v.z; st[cc][jj + 3] = v.w;
    }
    __syncthreads();
    {
        const int j = t >> 3, cb = (t & 7) * 4;
        short4 v = { f2bf(st[cb + 0][j]), f2bf(st[cb + 1][j]),
                     f2bf(st[cb + 2][j]), f2bf(st[cb + 3][j]) };
        *(short4*)(f2t + ((size_t)b * N2 + j0 + j) * C2 + c0 + cb) = v;
    }
}

// ---------------- MFMA GEMM -> Ykc [b][32][N1][8] bf16 + BN partials ----------------
// MODE 0: K=384. B rows [0,128) from f1 (f32); rows [128,384) interp from f2t (fused).
// MODE 1: K=256. B rows from y1kc, BN1+ReLU applied on load.
template<int MODE>
__global__ __launch_bounds__(512)
void gemm_kernel(const short* __restrict__ Wsw,
                 const float* __restrict__ X0, const short* __restrict__ X1,
                 const float4* __restrict__ pk,
                 const float* __restrict__ scale, const float* __restrict__ shift,
                 short* __restrict__ Ykc, float2* __restrict__ P) {
    constexpr int K = (MODE == 0) ? CIN : H;
    constexpr int NT = K / 32;

    __shared__ __align__(16) short A_lds[2][4][256][8];  // 32KB
    __shared__ __align__(16) short B_lds[2][4][128][8];  // 16KB
    __shared__ float sc_s[256], sh_s[256];
    __shared__ float2 pb[256][2];

    const int t = threadIdx.x;
    const int n0 = blockIdx.x * 128;
    const int b  = blockIdx.y;
    const int blkid = b * 32 + blockIdx.x;

    if (MODE == 1 && t < 256) { sc_s[t] = scale[t]; sh_s[t] = shift[t]; }

    const int sn  = t & 127;
    const int skb = t >> 7;
    const int lane = t & 63, wv = t >> 6;
    const int wm = wv >> 1, wn = wv & 1;
    const int l16 = lane & 15, lq = lane >> 4;
    const int am_base = wm * 64 + l16;
    const int bn_base = wn * 64 + l16;

    const float* X0b = (MODE == 0) ? X0 + (size_t)b * C1 * N1 : (const float*)nullptr;
    const short* f2tb = (MODE == 0) ? X1 + (size_t)b * N2 * C2 : (const short*)nullptr;
    const short* y1b  = (MODE == 1) ? X1 + (size_t)b * 32 * N1 * 8 : (const short*)nullptr;

    int gi0 = 0, gi1 = 0, gi2 = 0;
    float gw0 = 0.f, gw1 = 0.f, gw2 = 0.f;
    if (MODE == 0) {
        float4 v = pk[(size_t)b * N1 + n0 + sn];
        unsigned u = __float_as_uint(v.x);
        gi0 = u & 1023; gi1 = (u >> 10) & 1023; gi2 = (u >> 20) & 1023;
        gw0 = v.y; gw1 = v.z; gw2 = v.w;
    }

    f32x4 acc[4][4];
    #pragma unroll
    for (int i = 0; i < 4; ++i)
        #pragma unroll
        for (int j = 0; j < 4; ++j)
            acc[i][j] = (f32x4){0.f, 0.f, 0.f, 0.f};

    auto stageA = [&](int step, int bufi) {
        const short* g = Wsw + (size_t)step * 8192 + wv * 512 + lane * 8;
        short* l = &A_lds[bufi][0][0][0] + wv * 512;
        gll16(g, l);
        gll16(g + 4096, l + 4096);
    };

    auto compute = [&](int bufi) {
        bf16x8 a[4], bb[4];
        #pragma unroll
        for (int f = 0; f < 4; ++f) {
            a[f]  = *(const bf16x8*)&A_lds[bufi][lq][am_base + f * 16][0];
            bb[f] = *(const bf16x8*)&B_lds[bufi][lq][bn_base + f * 16][0];
        }
        #pragma unroll
        for (int i = 0; i < 4; ++i)
            #pragma unroll
            for (int j = 0; j < 4; ++j)
                acc[i][j] = __builtin_amdgcn_mfma_f32_16x16x32_bf16(a[i], bb[j], acc[i][j], 0, 0, 0);
    };

    __syncthreads();   // sc_s ready

    // ---- prologue: stage step 0 into buf 0 ----
    {
        float pf[8]; bf16x8 pg0, pg1, pg2, py;
        if (MODE == 0) {
            const float* src = X0b + (size_t)(skb * 8) * N1 + n0 + sn;  // step 0 < 4
            #pragma unroll
            for (int j = 0; j < 8; ++j) pf[j] = src[(size_t)j * N1];
        } else {
            py = *(const bf16x8*)(y1b + ((size_t)skb * N1 + n0 + sn) * 8);
        }
        stageA(0, 0);
        bf16x8 pv;
        if (MODE == 0) {
            #pragma unroll
            for (int j = 0; j < 8; ++j) pv[j] = f2bf(pf[j]);
        } else {
            const int gk = skb * 8;
            #pragma unroll
            for (int e = 0; e < 8; ++e)
                pv[e] = f2bf(fmaxf(fmaf(bf2f(py[e]), sc_s[gk + e], sh_s[gk + e]), 0.f));
        }
        *(bf16x8*)&B_lds[0][skb][sn][0] = pv;
        (void)pg0; (void)pg1; (void)pg2;
    }
    __syncthreads();   // buf0 ready (drains gll)

    int buf = 0;
    for (int s = 0; s < NT; ++s) {
        const bool has_next = (s + 1 < NT);
        const bool nearly = (MODE == 0) && (s + 1 < 4);
        float pf[8]; bf16x8 pg0, pg1, pg2, py;
        if (has_next) {
            // issue B loads for step s+1 (T14: consume after compute)
            if (MODE == 0) {
                if (nearly) {
                    const float* src = X0b + (size_t)((s + 1) * 32 + skb * 8) * N1 + n0 + sn;
                    #pragma unroll
                    for (int j = 0; j < 8; ++j) pf[j] = src[(size_t)j * N1];
                } else {
                    const int c0 = (s + 1) * 32 + skb * 8 - C1;
                    pg0 = *(const bf16x8*)(f2tb + (size_t)gi0 * C2 + c0);
                    pg1 = *(const bf16x8*)(f2tb + (size_t)gi1 * C2 + c0);
                    pg2 = *(const bf16x8*)(f2tb + (size_t)gi2 * C2 + c0);
                }
            } else {
                py = *(const bf16x8*)(y1b + ((size_t)((s + 1) * 4 + skb) * N1 + n0 + sn) * 8);
            }
            stageA(s + 1, buf ^ 1);
        }

        compute(buf);

        if (has_next) {
            bf16x8 pv;
            if (MODE == 0) {
                if (nearly) {
                    #pragma unroll
                    for (int j = 0; j < 8; ++j) pv[j] = f2bf(pf[j]);
                } else {
                    #pragma unroll
                    for (int e = 0; e < 8; ++e)
                        pv[e] = f2bf(fmaf(gw2, bf2f(pg2[e]),
                                     fmaf(gw1, bf2f(pg1[e]), gw0 * bf2f(pg0[e]))));
                }
            } else {
                const int gk = (s + 1) * 32 + skb * 8;
                #pragma unroll
                for (int e = 0; e < 8; ++e)
                    pv[e] = f2bf(fmaxf(fmaf(bf2f(py[e]), sc_s[gk + e], sh_s[gk + e]), 0.f));
            }
            *(bf16x8*)&B_lds[buf ^ 1][skb][sn][0] = pv;
        }
        __syncthreads();
        buf ^= 1;
    }

    // ---- epilogue: k-chunked store [kb][n][8] ----
    short* Yb = Ykc + (size_t)b * 32 * N1 * 8;
    #pragma unroll
    for (int i = 0; i < 4; ++i) {
        const int kb = wm * 8 + i * 2 + (lq >> 1);
        const int kr0 = (lq & 1) * 4;
        #pragma unroll
        for (int j = 0; j < 4; ++j) {
            const int n = n0 + wn * 64 + j * 16 + l16;
            short4 v = { f2bf(acc[i][j][0]), f2bf(acc[i][j][1]),
                         f2bf(acc[i][j][2]), f2bf(acc[i][j][3]) };
            *(short4*)(Yb + ((size_t)kb * N1 + n) * 8 + kr0) = v;
        }
    }

    // ---- BN partials: per-row (sum, sumsq) over this block's 128 cols ----
    #pragma unroll
    for (int i = 0; i < 4; ++i) {
        #pragma unroll
        for (int r = 0; r < 4; ++r) {
            float s = 0.f, qq = 0.f;
            #pragma unroll
            for (int j = 0; j < 4; ++j) {
                float xv = acc[i][j][r];
                s += xv; qq += xv * xv;
            }
            #pragma unroll
            for (int msk = 1; msk < 16; msk <<= 1) {
                s  += __shfl_xor(s, msk);
                qq += __shfl_xor(qq, msk);
            }
            if (l16 == 0)
                pb[wm * 64 + i * 16 + lq * 4 + r][wn] = make_float2(s, qq);
        }
    }
    __syncthreads();
    if (t < 256) {
        float2 a = pb[t][0], c = pb[t][1];
        P[(size_t)t * 512 + blkid] = make_float2(a.x + c.x, a.y + c.y);
    }
}

// ---------------- BN reduce: partials [256][512] -> scale/shift ----------------
__global__ __launch_bounds__(256)
void bn_reduce(const float2* __restrict__ P, const float* __restrict__ g,
               const float* __restrict__ be, float* __restrict__ scale,
               float* __restrict__ shift) {
    const int c = blockIdx.x, t = threadIdx.x;
    float2 v0 = P[(size_t)c * 512 + t];
    float2 v1 = P[(size_t)c * 512 + 256 + t];
    float s = v0.x + v1.x, q = v0.y + v1.y;
    __shared__ float ss[256], sq[256];
    ss[t] = s; sq[t] = q;
    __syncthreads();
    for (int o = 128; o > 0; o >>= 1) {
        if (t < o) { ss[t] += ss[t + o]; sq[t] += sq[t + o]; }
        __syncthreads();
    }
    if (t == 0) {
        const float inv = 1.0f / (float)(BATCH * N1);
        float mean = ss[0] * inv;
        float var  = sq[0] * inv - mean * mean;
        float sc = g[c] / sqrtf(var + BN_EPS);
        scale[c] = sc;
        shift[c] = be[c] - mean * sc;
    }
}

// ---------------- Final BN2+ReLU: y2kc -> f32 out (normal layout) ----------------
__global__ __launch_bounds__(256)
void final_bn_relu(const short* __restrict__ y2kc, const float* __restrict__ scale,
                   const float* __restrict__ shift, float* __restrict__ out) {
    const int t = threadIdx.x;
    const int n0 = blockIdx.x * 1024 + t * 4;
    const int kb = blockIdx.y, b = blockIdx.z;
    const short* src = y2kc + ((size_t)(b * 32 + kb) * N1 + n0) * 8;
    bf16x8 v0 = *(const bf16x8*)(src);
    bf16x8 v1 = *(const bf16x8*)(src + 8);
    bf16x8 v2 = *(const bf16x8*)(src + 16);
    bf16x8 v3 = *(const bf16x8*)(src + 24);
    #pragma unroll
    for (int e = 0; e < 8; ++e) {
        const float sc = scale[kb * 8 + e], sh = shift[kb * 8 + e];
        float4 o;
        o.x = fmaxf(fmaf(bf2f(v0[e]), sc, sh), 0.f);
        o.y = fmaxf(fmaf(bf2f(v1[e]), sc, sh), 0.f);
        o.z = fmaxf(fmaf(bf2f(v2[e]), sc, sh), 0.f);
        o.w = fmaxf(fmaf(bf2f(v3[e]), sc, sh), 0.f);
        *(float4*)(out + ((size_t)(b * 256 + kb * 8 + e) * N1) + n0) = o;
    }
}

extern "C" void kernel_launch(void* const* d_in, const int* in_sizes, int n_in,
                              void* d_out, int out_size, void* d_ws, size_t ws_size,
                              hipStream_t stream) {
    const float* c1  = (const float*)d_in[0];
    const float* c2  = (const float*)d_in[1];
    const float* f1  = (const float*)d_in[2];
    const float* f2  = (const float*)d_in[3];
    const float* W1  = (const float*)d_in[4];
    const float* g1  = (const float*)d_in[6];
    const float* be1 = (const float*)d_in[7];
    const float* W2  = (const float*)d_in[8];
    const float* g2  = (const float*)d_in[10];
    const float* be2 = (const float*)d_in[11];
    float* out = (float*)d_out;

    // ws layout (y2kc region hosts f2t/W1s/pk, all dead before gemm2 writes y2kc)
    char* ws = (char*)d_ws;
    short*  y2kc = (short*)ws;                             // [0, 32MB)
    short*  f2t  = (short*)ws;                             // [0, 8MB)
    short*  W1s  = (short*)(ws + (8u << 20));              // 192KB
    float4* pk   = (float4*)(ws + (9u << 20));             // 1MB
    short*  y1kc = (short*)(ws + (32u << 20));             // 32MB
    short*  W2s  = (short*)(ws + (64u << 20));             // 128KB
    float2* P    = (float2*)(ws + (64u << 20) + (256u << 10)); // 1MB
    float* scale1 = (float*)(ws + (64u << 20) + (256u << 10) + (1u << 20));
    float* shift1 = scale1 + 256;
    float* scale2 = shift1 + 256;
    float* shift2 = scale2 + 256;

    prep_w<<<48, 256, 0, stream>>>(W1, W1s, CIN);
    prep_w<<<32, 256, 0, stream>>>(W2, W2s, H);
    transpose_f2<<<dim3(N2 / 32, C2 / 32, BATCH), 256, 0, stream>>>(f2, f2t);
    knn_kernel<<<dim3(N1 / 64, BATCH), 256, 0, stream>>>(c1, c2, pk);

    gemm_kernel<0><<<dim3(N1 / 128, BATCH), 512, 0, stream>>>(
        W1s, f1, f2t, pk, nullptr, nullptr, y1kc, P);
    bn_reduce<<<256, 256, 0, stream>>>(P, g1, be1, scale1, shift1);

    gemm_kernel<1><<<dim3(N1 / 128, BATCH), 512, 0, stream>>>(
        W2s, nullptr, y1kc, nullptr, scale1, shift1, y2kc, P);
    bn_reduce<<<256, 256, 0, stream>>>(P, g2, be2, scale2, shift2);

    final_bn_relu<<<dim3(N1 / 1024, 32, BATCH), 256, 0, stream>>>(y2kc, scale2, shift2, out);
}